// Round 1
// baseline (423.436 us; speedup 1.0000x reference)
//
#include <hip/hip_runtime.h>

#define M_DIM 4096
#define K_DIM 16384
#define N_DIM 256
#define SPLIT 16
#define BK 64
#define KSLICE (K_DIM / SPLIT)  // 1024
#define NITER (KSLICE / BK)     // 16

typedef __bf16 bf16x8 __attribute__((ext_vector_type(8)));
typedef __bf16 bf16x4 __attribute__((ext_vector_type(4)));
typedef float f32x4 __attribute__((ext_vector_type(4)));

// ---------------- W transpose + convert: Wt[n][k] = bf16(W[k][n]) ----------------
__global__ __launch_bounds__(256) void wt_kernel(const float* __restrict__ W,
                                                 __bf16* __restrict__ Wt) {
  __shared__ float tile[64][65];
  const int k0 = blockIdx.x * 64, n0 = blockIdx.y * 64;
  const int t = threadIdx.x;
#pragma unroll
  for (int r = 0; r < 4; ++r) {
    int idx4 = r * 256 + t;
    int kr = idx4 >> 4, c4 = idx4 & 15;
    f32x4 v = *(const f32x4*)(W + (size_t)(k0 + kr) * N_DIM + n0 + c4 * 4);
#pragma unroll
    for (int j = 0; j < 4; ++j) tile[kr][c4 * 4 + j] = v[j];
  }
  __syncthreads();
#pragma unroll
  for (int r = 0; r < 4; ++r) {
    int nr = (t >> 4) + r * 16, k4 = t & 15;
    bf16x4 o;
#pragma unroll
    for (int j = 0; j < 4; ++j) o[j] = (__bf16)tile[k4 * 4 + j][nr];
    *(bf16x4*)(Wt + (size_t)(n0 + nr) * K_DIM + k0 + k4 * 4) = o;
  }
}

// ---------------- Main MFMA GEMM: global->reg->LDS software pipeline ----------------
// BM=64, BN=256, BK=64, 256 thr = 4 waves; wave w owns 64m x 64n at n=w*64
// (4x4 tiles of mfma_f32_16x16x32_bf16). Loads for iter k+1 are issued after the
// LDS-ready barrier of iter k and complete under the MFMA phase.
// LDS = As 64x72 (9 KiB) + Bs 256x72 (36 KiB) = 45 KiB -> 3 blocks/CU.
// SPLIT=16 -> grid 1024 blocks -> 3 resident blocks/CU (was 2 with SPLIT=8):
// cross-block overlap is what hides the per-block barrier/vmcnt drains.
__global__ __launch_bounds__(256, 3) void gemm_kernel(const float* __restrict__ x,
                                                      const __bf16* __restrict__ Wt,
                                                      __bf16* __restrict__ part) {
  __shared__ __bf16 As[64 * 72];
  __shared__ __bf16 Bs[256 * 72];

  const int t = threadIdx.x;
  const int l = t & 63;
  const int w = t >> 6;
  const int la = l & 15, q = l >> 4;
  const int m0 = blockIdx.x * 64;
  const int kbase = blockIdx.y * KSLICE;

  // A staging: 4 float4/thread covering 64 rows x 64 k
  const int arow = t >> 4, ac4 = t & 15;
  // B staging: 8 x 16B/thread covering 256 rows x 64 k (8 lanes per 128B row seg)
  const int bn = t >> 3, bk8 = (t & 7) * 8;

  const float* ap = x + (size_t)(m0 + arow) * K_DIM + kbase + ac4 * 4;
  const __bf16* bp = Wt + (size_t)bn * K_DIM + kbase + bk8;

  f32x4 areg[4];
  bf16x8 breg[8];

  // prologue: prefetch iter 0 (x is stream-once: NT loads keep Wt resident in L2)
#pragma unroll
  for (int r = 0; r < 4; ++r)
    areg[r] = __builtin_nontemporal_load((const f32x4*)(ap + (size_t)r * 16 * K_DIM));
#pragma unroll
  for (int c = 0; c < 8; ++c) breg[c] = *(const bf16x8*)(bp + (size_t)c * 32 * K_DIM);

  f32x4 acc[4][4];
  const f32x4 zero = {0.f, 0.f, 0.f, 0.f};
#pragma unroll
  for (int i = 0; i < 4; ++i)
#pragma unroll
    for (int j = 0; j < 4; ++j) acc[i][j] = zero;

  for (int it = 0; it < NITER; ++it) {
    __syncthreads();  // previous MFMA phase done reading LDS
    // ---- commit prefetched regs to LDS (compiler waits vmcnt here, per-wave) ----
#pragma unroll
    for (int r = 0; r < 4; ++r) {
      bf16x4 o = {(__bf16)areg[r][0], (__bf16)areg[r][1],
                  (__bf16)areg[r][2], (__bf16)areg[r][3]};
      *(bf16x4*)(&As[(arow + r * 16) * 72 + ac4 * 4]) = o;
    }
#pragma unroll
    for (int c = 0; c < 8; ++c)
      *(bf16x8*)(&Bs[(bn + c * 32) * 72 + bk8]) = breg[c];
    __syncthreads();  // LDS ready

    // ---- issue next iteration's global loads; they fly under the MFMAs ----
    if (it + 1 < NITER) {
      ap += BK;
      bp += BK;
#pragma unroll
      for (int r = 0; r < 4; ++r)
        areg[r] = __builtin_nontemporal_load((const f32x4*)(ap + (size_t)r * 16 * K_DIM));
#pragma unroll
      for (int c = 0; c < 8; ++c) breg[c] = *(const bf16x8*)(bp + (size_t)c * 32 * K_DIM);
    }

    // ---- 32 MFMAs per wave ----
#pragma unroll
    for (int ks = 0; ks < 2; ++ks) {
      const int kb = ks * 32 + q * 8;
      bf16x8 a[4], b[4];
#pragma unroll
      for (int i = 0; i < 4; ++i)
        a[i] = *(const bf16x8*)(&As[(i * 16 + la) * 72 + kb]);
#pragma unroll
      for (int j = 0; j < 4; ++j)
        b[j] = *(const bf16x8*)(&Bs[(w * 64 + j * 16 + la) * 72 + kb]);
#pragma unroll
      for (int i = 0; i < 4; ++i)
#pragma unroll
        for (int j = 0; j < 4; ++j)
          acc[i][j] = __builtin_amdgcn_mfma_f32_16x16x32_bf16(a[i], b[j], acc[i][j], 0, 0, 0);
    }
  }

  // ---- epilogue: bf16 partials (C/D layout: col=lane&15, row=quad*4+reg) ----
  // NT stores: partials are write-once/read-once, keep them out of L2.
  __bf16* pbase = part + (size_t)blockIdx.y * ((size_t)M_DIM * N_DIM);
#pragma unroll
  for (int i = 0; i < 4; ++i) {
    int r0 = m0 + i * 16 + q * 4;
#pragma unroll
    for (int j = 0; j < 4; ++j) {
      int c = w * 64 + j * 16 + la;
#pragma unroll
      for (int r = 0; r < 4; ++r)
        __builtin_nontemporal_store((__bf16)acc[i][j][r],
                                    &pbase[(size_t)(r0 + r) * N_DIM + c]);
    }
  }
}

// ---------------- reduce partials + exact fp32 bit-flip correction + bias ----------------
__global__ __launch_bounds__(256) void reduce_kernel(const __bf16* __restrict__ part,
                                                     const float* __restrict__ x,
                                                     const float* __restrict__ W,
                                                     const float* __restrict__ bvec,
                                                     const float* __restrict__ coeffp,
                                                     const int* __restrict__ idx,
                                                     const int* __restrict__ bp,
                                                     float* __restrict__ out) {
  const int row = blockIdx.x;
  const int o = threadIdx.x;
  const int iv = idx[row];
  const float g = x[(size_t)row * K_DIM + iv];
  const int bits = __float_as_int(g) ^ (1 << bp[row]);
  const float upd = __int_as_float(bits) - g;  // swap_sim(g) - g, exact fp32
  const float coeff = coeffp[0];
  const size_t off = (size_t)row * N_DIM + o;
  float sum = 0.f;
#pragma unroll
  for (int s = 0; s < SPLIT; ++s)
    sum += (float)__builtin_nontemporal_load(
        &part[(size_t)s * ((size_t)M_DIM * N_DIM) + off]);
  out[off] = sum + coeff * upd * W[(size_t)iv * N_DIM + o] + bvec[o];
}

extern "C" void kernel_launch(void* const* d_in, const int* in_sizes, int n_in,
                              void* d_out, int out_size, void* d_ws, size_t ws_size,
                              hipStream_t stream) {
  const float* x = (const float*)d_in[0];
  const float* W = (const float*)d_in[1];
  const float* b = (const float*)d_in[2];
  const float* coeff = (const float*)d_in[3];
  const int* idx = (const int*)d_in[4];
  const int* bp = (const int*)d_in[5];
  float* out = (float*)d_out;

  __bf16* Wt = (__bf16*)d_ws;
  const size_t wt_bytes = (size_t)K_DIM * N_DIM * 2;  // 8 MiB
  __bf16* part = (__bf16*)((char*)d_ws + wt_bytes);   // SPLIT x 2 MiB bf16 partials

  hipLaunchKernelGGL(wt_kernel, dim3(K_DIM / 64, N_DIM / 64), dim3(256), 0, stream, W, Wt);
  hipLaunchKernelGGL(gemm_kernel, dim3(M_DIM / 64, SPLIT), dim3(256), 0, stream,
                     x, Wt, part);
  hipLaunchKernelGGL(reduce_kernel, dim3(M_DIM), dim3(256), 0, stream,
                     part, x, W, b, coeff, idx, bp, out);
}

// Round 2
// 422.884 us; speedup vs baseline: 1.0013x; 1.0013x over previous
//
#include <hip/hip_runtime.h>
#include <cstdint>

#define M_DIM 4096
#define K_DIM 16384
#define N_DIM 256
#define SPLIT 8
#define BK 64
#define KSLICE (K_DIM / SPLIT)
#define NITER (KSLICE / BK)  // 32
#define BTILE 16384          // 256*64 bf16 elements per B K-tile (32 KiB)

typedef __bf16 bf16x8 __attribute__((ext_vector_type(8)));
typedef __bf16 bf16x4 __attribute__((ext_vector_type(4)));
typedef float f32x4 __attribute__((ext_vector_type(4)));

// ---------------- W transpose + convert, SWIZZLED for gemm's global_load_lds ----
// Wt2 layout: [tile = k/64][n][ (k%64) ^ ((n&7)<<3) ]  (bf16)
// gemm DMA-copies one 32KB tile linearly into LDS; the XOR (baked into storage)
// makes the gemm's strided ds_read_b128 fragment reads bank-conflict-free.
__global__ __launch_bounds__(256) void wt_kernel(const float* __restrict__ W,
                                                 __bf16* __restrict__ Wt2) {
  __shared__ float tile[64][65];
  const int k0 = blockIdx.x * 64, n0 = blockIdx.y * 64;
  const int t = threadIdx.x;
#pragma unroll
  for (int r = 0; r < 4; ++r) {
    int idx4 = r * 256 + t;
    int kr = idx4 >> 4, c4 = idx4 & 15;
    f32x4 v = *(const f32x4*)(W + (size_t)(k0 + kr) * N_DIM + n0 + c4 * 4);
#pragma unroll
    for (int j = 0; j < 4; ++j) tile[kr][c4 * 4 + j] = v[j];
  }
  __syncthreads();
  const size_t obase = (size_t)blockIdx.x * ((size_t)N_DIM * 64);  // tile index = k0/64
#pragma unroll
  for (int r = 0; r < 4; ++r) {
    int nr = (t >> 4) + r * 16, k4 = t & 15;
    int n = n0 + nr;
    bf16x4 o;
#pragma unroll
    for (int j = 0; j < 4; ++j) o[j] = (__bf16)tile[k4 * 4 + j][nr];
    int kk = (k4 * 4) ^ ((n & 7) << 3);  // 4-aligned chunk survives the XOR (bits 3..5)
    *(bf16x4*)(Wt2 + obase + (size_t)n * 64 + kk) = o;
  }
}

// ---------------- Main MFMA GEMM: deep pipeline, raw barriers, counted vmcnt ----
// BM=64, BN=256, BK=64, 256 thr = 4 waves; wave w owns 64m x 64n at n=w*64.
// A: fp32 global -> regs (2 iterations deep) -> cvt -> LDS (padded, single buf).
// B: bf16 Wt2 tile -> global_load_lds DMA (1 iteration early) -> LDS (linear, dbuf).
// Raw s_barrier + counted s_waitcnt keep 4 A-loads in flight ACROSS both barriers.
// LDS = 9KB As + 64KB Bs = 73KB -> 2 blocks/CU (matches 512-block grid).
__global__ __launch_bounds__(256, 2) void gemm_kernel(const float* __restrict__ x,
                                                      const __bf16* __restrict__ Wt2,
                                                      __bf16* __restrict__ part) {
  __shared__ __bf16 As[64 * 72];
  __shared__ __bf16 Bs[2 * BTILE];

  const int t = threadIdx.x;
  const int l = t & 63;
  const int w = t >> 6;
  const int la = l & 15, q = l >> 4;
  const int kx = (la & 7) << 3;  // read-side XOR matching Wt2's storage swizzle
  const int m0 = blockIdx.x * 64;
  const int tile0 = blockIdx.y * (KSLICE / 64);

  // A staging: 4 float4/thread covering 64 rows x 64 k
  const int arow = t >> 4, ac4 = t & 15;
  const float* ap = x + (size_t)(m0 + arow) * K_DIM + (size_t)blockIdx.y * KSLICE + ac4 * 4;

  // B DMA: 32 chunks of 1KB per tile; chunk c = i*4 + w (wave-uniform LDS dest)
  const uint8_t* bgbase = (const uint8_t*)(Wt2 + (size_t)tile0 * BTILE);

  f32x4 aregA[4], aregB[4];

  // ---- prologue: B(0) -> Bs buf0 (DMA), A(0) -> aregA, A(1) -> aregB ----
#pragma unroll
  for (int i = 0; i < 8; ++i) {
    const int c = i * 4 + w;
    __builtin_amdgcn_global_load_lds(
        (const __attribute__((address_space(1))) void*)(bgbase + c * 1024 + l * 16),
        (__attribute__((address_space(3))) void*)((uint8_t*)Bs + c * 1024),
        16, 0, 0);
  }
#pragma unroll
  for (int r = 0; r < 4; ++r) aregA[r] = *(const f32x4*)(ap + (size_t)r * 16 * K_DIM);
  ap += BK;
#pragma unroll
  for (int r = 0; r < 4; ++r) aregB[r] = *(const f32x4*)(ap + (size_t)r * 16 * K_DIM);

  f32x4 acc[4][4];
  const f32x4 zero = {0.f, 0.f, 0.f, 0.f};
#pragma unroll
  for (int i = 0; i < 4; ++i)
#pragma unroll
    for (int j = 0; j < 4; ++j) acc[i][j] = zero;

  // Per-iteration waitcnt ledger (issue order is oldest-first):
  //   at the pre-barrier wait of iter k, outstanding = B(k)[8], A(k+1)[4]
  //   -> s_waitcnt vmcnt(4) drains exactly B(k), keeps A(k+1) flying.
  //   Commit of A(k) waits (compiler-inserted, reg dep) on loads issued @k-2: no stall.
#define GEMM_ITER(IT, AREG, RBUF, WBUF)                                              \
  {                                                                                  \
    __builtin_amdgcn_s_barrier(); /* prev MFMA reads of As/Bs[RBUF^1] done */        \
    _Pragma("unroll") for (int r = 0; r < 4; ++r) {                                  \
      bf16x4 o = {(__bf16)AREG[r][0], (__bf16)AREG[r][1],                            \
                  (__bf16)AREG[r][2], (__bf16)AREG[r][3]};                           \
      *(bf16x4*)(&As[(arow + r * 16) * 72 + ac4 * 4]) = o;                           \
    }                                                                                \
    if ((IT) + 1 < NITER)                                                            \
      asm volatile("s_waitcnt vmcnt(4) lgkmcnt(0)" ::: "memory");                    \
    else                                                                             \
      asm volatile("s_waitcnt vmcnt(0) lgkmcnt(0)" ::: "memory");                    \
    __builtin_amdgcn_s_barrier(); /* As + Bs[RBUF] ready for all waves */            \
    if ((IT) + 1 < NITER) {                                                          \
      _Pragma("unroll") for (int i = 0; i < 8; ++i) {                                \
        const int c = i * 4 + w;                                                     \
        __builtin_amdgcn_global_load_lds(                                            \
            (const __attribute__((address_space(1))) void*)(                         \
                bgbase + ((IT) + 1) * 32768 + c * 1024 + l * 16),                    \
            (__attribute__((address_space(3))) void*)(                               \
                (uint8_t*)Bs + (WBUF)*32768 + c * 1024),                             \
            16, 0, 0);                                                               \
      }                                                                              \
    }                                                                                \
    if ((IT) + 2 < NITER) { /* refill same reg set for iter IT+2 */                  \
      ap += BK;                                                                      \
      _Pragma("unroll") for (int r = 0; r < 4; ++r)                                  \
          AREG[r] = *(const f32x4*)(ap + (size_t)r * 16 * K_DIM);                    \
    }                                                                                \
    const __bf16* bsb = Bs + (RBUF)*BTILE;                                           \
    _Pragma("unroll") for (int ks = 0; ks < 2; ++ks) {                               \
      const int kb = ks * 32 + q * 8;                                                \
      bf16x8 a[4], b[4];                                                             \
      _Pragma("unroll") for (int i = 0; i < 4; ++i)                                  \
          a[i] = *(const bf16x8*)(&As[(i * 16 + la) * 72 + kb]);                     \
      _Pragma("unroll") for (int j = 0; j < 4; ++j)                                  \
          b[j] = *(const bf16x8*)(&bsb[(w * 64 + j * 16 + la) * 64 + (kb ^ kx)]);    \
      _Pragma("unroll") for (int i = 0; i < 4; ++i)                                  \
          _Pragma("unroll") for (int j = 0; j < 4; ++j)                              \
              acc[i][j] =                                                            \
          __builtin_amdgcn_mfma_f32_16x16x32_bf16(a[i], b[j], acc[i][j], 0, 0, 0);   \
    }                                                                                \
  }

  for (int it = 0; it < NITER; it += 2) {
    GEMM_ITER(it, aregA, 0, 1);
    GEMM_ITER(it + 1, aregB, 1, 0);
  }
#undef GEMM_ITER

  // ---- epilogue: bf16 partials (C/D layout: col=lane&15, row=quad*4+reg) ----
  __bf16* pbase = part + (size_t)blockIdx.y * ((size_t)M_DIM * N_DIM);
#pragma unroll
  for (int i = 0; i < 4; ++i) {
    int r0 = m0 + i * 16 + q * 4;
#pragma unroll
    for (int j = 0; j < 4; ++j) {
      int c = w * 64 + j * 16 + la;
#pragma unroll
      for (int r = 0; r < 4; ++r)
        pbase[(size_t)(r0 + r) * N_DIM + c] = (__bf16)acc[i][j][r];
    }
  }
}

// ---------------- reduce partials + exact fp32 bit-flip correction + bias ----------------
__global__ __launch_bounds__(256) void reduce_kernel(const __bf16* __restrict__ part,
                                                     const float* __restrict__ x,
                                                     const float* __restrict__ W,
                                                     const float* __restrict__ bvec,
                                                     const float* __restrict__ coeffp,
                                                     const int* __restrict__ idx,
                                                     const int* __restrict__ bp,
                                                     float* __restrict__ out) {
  const int row = blockIdx.x;
  const int o = threadIdx.x;
  const int iv = idx[row];
  const float g = x[(size_t)row * K_DIM + iv];
  const int bits = __float_as_int(g) ^ (1 << bp[row]);
  const float upd = __int_as_float(bits) - g;  // swap_sim(g) - g, exact fp32
  const float coeff = coeffp[0];
  const size_t off = (size_t)row * N_DIM + o;
  float sum = 0.f;
#pragma unroll
  for (int s = 0; s < SPLIT; ++s)
    sum += (float)part[(size_t)s * ((size_t)M_DIM * N_DIM) + off];
  out[off] = sum + coeff * upd * W[(size_t)iv * N_DIM + o] + bvec[o];
}

extern "C" void kernel_launch(void* const* d_in, const int* in_sizes, int n_in,
                              void* d_out, int out_size, void* d_ws, size_t ws_size,
                              hipStream_t stream) {
  const float* x = (const float*)d_in[0];
  const float* W = (const float*)d_in[1];
  const float* b = (const float*)d_in[2];
  const float* coeff = (const float*)d_in[3];
  const int* idx = (const int*)d_in[4];
  const int* bp = (const int*)d_in[5];
  float* out = (float*)d_out;

  __bf16* Wt2 = (__bf16*)d_ws;
  const size_t wt_bytes = (size_t)K_DIM * N_DIM * 2;  // 8 MiB
  __bf16* part = (__bf16*)((char*)d_ws + wt_bytes);   // SPLIT x 2 MiB bf16 partials

  hipLaunchKernelGGL(wt_kernel, dim3(K_DIM / 64, N_DIM / 64), dim3(256), 0, stream, W, Wt2);
  hipLaunchKernelGGL(gemm_kernel, dim3(M_DIM / 64, SPLIT), dim3(256), 0, stream,
                     x, Wt2, part);
  hipLaunchKernelGGL(reduce_kernel, dim3(M_DIM), dim3(256), 0, stream,
                     part, x, W, b, coeff, idx, bp, out);
}